// Round 1
// baseline (296.771 us; speedup 1.0000x reference)
//
#include <hip/hip_runtime.h>
#include <hip/hip_bf16.h>

typedef unsigned short ushort_t;
typedef __attribute__((ext_vector_type(4))) float v4f;
typedef __attribute__((ext_vector_type(8))) short v8s;

#define FDIM 128
#define KCLUST 16
#define CSTRIDE 264   // combined-row stride in bf16 elems (264*2B = 528B -> rows offset by 4 banks)

__device__ __forceinline__ ushort_t f2bf(float x) {
    unsigned int u = __float_as_uint(x);
    unsigned int r = (u + 0x7fffu + ((u >> 16) & 1u)) >> 16;
    return (ushort_t)r;
}

__device__ __forceinline__ float wave_reduce_sum(float v) {
    #pragma unroll
    for (int off = 32; off > 0; off >>= 1) v += __shfl_xor(v, off, 64);
    return v;
}

// ---------------------------------------------------------------------------
// Kernel 1: cast weight (E x 256 f32) -> bf16, padded to Np rows (zeros).
// ---------------------------------------------------------------------------
__global__ void pack_weight(const float* __restrict__ W, ushort_t* __restrict__ Wb,
                            long total, long valid) {
    long i = ((long)blockIdx.x * blockDim.x + threadIdx.x) * 4;
    if (i >= total) return;
    float4 v;
    if (i < valid) v = *(const float4*)(W + i);
    else           v = make_float4(0.f, 0.f, 0.f, 0.f);
    ushort_t* dst = Wb + i;
    dst[0] = f2bf(v.x); dst[1] = f2bf(v.y); dst[2] = f2bf(v.z); dst[3] = f2bf(v.w);
}

// ---------------------------------------------------------------------------
// Kernel 2 (fused), v2: 512 threads = 8 waves per block of 16 rows.
//   phase A: each wave owns TWO rows, processed as interleaved independent
//     dependency chains (2x ILP on shuffles/LDS round-trips/gathers).
//     Neighbor indices are preloaded into lanes and broadcast via __shfl,
//     removing the dependent index load from the per-iteration chain.
//   phase B: out[16][E] = relu(combined @ Wb^T) via mfma 16x16x32 bf16;
//     each wave's first W tile is prefetched into VGPRs BEFORE the barrier.
// ---------------------------------------------------------------------------
__global__ __launch_bounds__(512, 4) void fused_agg(
    const int* __restrict__ nodes, const int* __restrict__ neigh_idx,
    const float* __restrict__ self_table, const float* __restrict__ neigh_table,
    const float* __restrict__ center, const float* __restrict__ cluster_mask,
    const float* __restrict__ alpha, const ushort_t* __restrict__ Wb,
    float* __restrict__ out, int B, int S, int E) {

    __shared__ __align__(16) ushort_t comb[16 * CSTRIDE];
    __shared__ __align__(16) float nbuf[16 * 144];   // per-row swizzled neigh vec
    __shared__ __align__(16) float qbuf[16 * 16];    // per-row q[16]

    const int t = threadIdx.x;
    const int lane = t & 63, wave = t >> 6;   // 8 waves
    const int kcl = lane & 15, blk = lane >> 4;

    // per-lane constants (feature layout: this lane owns features lane, lane+64)
    const float as0 = alpha[lane],       as1 = alpha[lane + 64];
    const float an0 = alpha[128 + lane], an1 = alpha[192 + lane];

    // center in cluster layout: cc[j] = center[kcl][blk*32 + j]
    float cc[32];
    {
        const float* cb = center + kcl * FDIM + blk * 32;
        #pragma unroll
        for (int j = 0; j < 32; j += 4) {
            float4 v = *(const float4*)(cb + j);
            cc[j] = v.x; cc[j+1] = v.y; cc[j+2] = v.z; cc[j+3] = v.w;
        }
    }
    // mask in feature layout: mk0[k] = mask[k][lane], mk1[k] = mask[k][lane+64]
    float mk0[KCLUST], mk1[KCLUST];
    #pragma unroll
    for (int kk = 0; kk < KCLUST; kk++) {
        mk0[kk] = cluster_mask[kk * FDIM + lane];
        mk1[kk] = cluster_mask[kk * FDIM + 64 + lane];
    }

    const int b0 = blockIdx.x * 16;
    const int rA = wave * 2, rB = rA + 1;
    int bA = b0 + rA, bB = b0 + rB;
    if (bA >= B) bA = B - 1;   // clamp loads; stores are guarded (B%16==0 here)
    if (bB >= B) bB = B - 1;

    float* const nbA = nbuf + rA * 144;
    float* const nbB = nbuf + rB * 144;
    float* const qbA = qbuf + rA * 16;
    float* const qbB = qbuf + rB * 16;

    // ---------------- phase A ----------------
    float lsA, lsB;
    {
        size_t ndA = (size_t)nodes[bA], ndB = (size_t)nodes[bB];
        float sA0 = self_table[ndA * FDIM + lane];
        float sA1 = self_table[ndA * FDIM + 64 + lane];
        float sB0 = self_table[ndB * FDIM + lane];
        float sB1 = self_table[ndB * FDIM + 64 + lane];
        lsA = wave_reduce_sum(sA0 * as0 + sA1 * as1);
        lsB = wave_reduce_sum(sB0 * as0 + sB1 * as1);
        ushort_t* crA = comb + rA * CSTRIDE;
        ushort_t* crB = comb + rB * CSTRIDE;
        crA[lane] = f2bf(sA0); crA[lane + 64] = f2bf(sA1);
        crB[lane] = f2bf(sB0); crB[lane + 64] = f2bf(sB1);
    }

    // preload neighbor indices into lanes (S <= 64; S=10 here)
    int gIA = 0, gIB = 0;
    if (lane < S) {
        gIA = neigh_idx[(size_t)bA * S + lane];
        gIB = neigh_idx[(size_t)bB * S + lane];
    }

    float accA0 = 0.f, accA1 = 0.f, asumA = 0.f;
    float accB0 = 0.f, accB1 = 0.f, asumB = 0.f;

    // software pipeline: preload s=0 for both rows
    int iA = __shfl(gIA, 0, 64);
    int iB = __shfl(gIB, 0, 64);
    float nA0 = neigh_table[(size_t)iA * FDIM + lane];
    float nA1 = neigh_table[(size_t)iA * FDIM + 64 + lane];
    float nB0 = neigh_table[(size_t)iB * FDIM + lane];
    float nB1 = neigh_table[(size_t)iB * FDIM + 64 + lane];

    for (int s = 0; s < S; s++) {
        const float cA0 = nA0, cA1 = nA1, cB0 = nB0, cB1 = nB1;
        if (s + 1 < S) {
            iA = __shfl(gIA, s + 1, 64);
            iB = __shfl(gIB, s + 1, 64);
            nA0 = neigh_table[(size_t)iA * FDIM + lane];
            nA1 = neigh_table[(size_t)iA * FDIM + 64 + lane];
            nB0 = neigh_table[(size_t)iB * FDIM + lane];
            nB1 = neigh_table[(size_t)iB * FDIM + 64 + lane];
        }
        // stage neigh vecs (swizzled: float f at idx f + (f>>5)*4)
        {
            const int f1 = lane + (lane >> 5) * 4;
            const int f2 = (lane + 64) + ((lane + 64) >> 5) * 4;
            nbA[f1] = cA0; nbA[f2] = cA1;
            nbB[f1] = cB0; nbB[f2] = cB1;
        }
        // attention logits, both rows (interleaved butterflies)
        float lnA = cA0 * an0 + cA1 * an1;
        float lnB = cB0 * an0 + cB1 * an1;
        #pragma unroll
        for (int off = 32; off > 0; off >>= 1) {
            lnA += __shfl_xor(lnA, off, 64);
            lnB += __shfl_xor(lnB, off, 64);
        }
        const float attA = __expf(fmaxf(lsA + lnA, 0.f));
        const float attB = __expf(fmaxf(lsB + lnB, 0.f));

        // cluster layout: d_k = sum_j (n_j - c_kj)^2 over this blk's 32 feats
        float dA = 0.f, dB = 0.f;
        {
            const float* na = nbA + blk * 36;
            const float* nb2 = nbB + blk * 36;
            #pragma unroll
            for (int i = 0; i < 8; i++) {
                float4 a4 = *(const float4*)(na + i * 4);
                float4 b4 = *(const float4*)(nb2 + i * 4);
                float u;
                u = a4.x - cc[i*4+0]; dA = fmaf(u, u, dA);
                u = a4.y - cc[i*4+1]; dA = fmaf(u, u, dA);
                u = a4.z - cc[i*4+2]; dA = fmaf(u, u, dA);
                u = a4.w - cc[i*4+3]; dA = fmaf(u, u, dA);
                u = b4.x - cc[i*4+0]; dB = fmaf(u, u, dB);
                u = b4.y - cc[i*4+1]; dB = fmaf(u, u, dB);
                u = b4.z - cc[i*4+2]; dB = fmaf(u, u, dB);
                u = b4.w - cc[i*4+3]; dB = fmaf(u, u, dB);
            }
        }
        dA += __shfl_xor(dA, 16, 64); dA += __shfl_xor(dA, 32, 64);
        dB += __shfl_xor(dB, 16, 64); dB += __shfl_xor(dB, 32, 64);
        const float qA = 1.0f / (dA + 1.0f);
        const float qB = 1.0f / (dB + 1.0f);
        if (lane < 16) { qbA[lane] = qA; qbB[lane] = qB; }

        // feature layout: m_f = sum_k q_k * mask[k][f]  (A then B to limit regs)
        float mA0, mA1;
        {
            float4 q0 = *(const float4*)(qbA + 0);
            float4 q1 = *(const float4*)(qbA + 4);
            float4 q2 = *(const float4*)(qbA + 8);
            float4 q3 = *(const float4*)(qbA + 12);
            mA0  = q0.x*mk0[0]  + q0.y*mk0[1]  + q0.z*mk0[2]  + q0.w*mk0[3];
            mA0 += q1.x*mk0[4]  + q1.y*mk0[5]  + q1.z*mk0[6]  + q1.w*mk0[7];
            mA0 += q2.x*mk0[8]  + q2.y*mk0[9]  + q2.z*mk0[10] + q2.w*mk0[11];
            mA0 += q3.x*mk0[12] + q3.y*mk0[13] + q3.z*mk0[14] + q3.w*mk0[15];
            mA1  = q0.x*mk1[0]  + q0.y*mk1[1]  + q0.z*mk1[2]  + q0.w*mk1[3];
            mA1 += q1.x*mk1[4]  + q1.y*mk1[5]  + q1.z*mk1[6]  + q1.w*mk1[7];
            mA1 += q2.x*mk1[8]  + q2.y*mk1[9]  + q2.z*mk1[10] + q2.w*mk1[11];
            mA1 += q3.x*mk1[12] + q3.y*mk1[13] + q3.z*mk1[14] + q3.w*mk1[15];
        }
        float mB0, mB1;
        {
            float4 q0 = *(const float4*)(qbB + 0);
            float4 q1 = *(const float4*)(qbB + 4);
            float4 q2 = *(const float4*)(qbB + 8);
            float4 q3 = *(const float4*)(qbB + 12);
            mB0  = q0.x*mk0[0]  + q0.y*mk0[1]  + q0.z*mk0[2]  + q0.w*mk0[3];
            mB0 += q1.x*mk0[4]  + q1.y*mk0[5]  + q1.z*mk0[6]  + q1.w*mk0[7];
            mB0 += q2.x*mk0[8]  + q2.y*mk0[9]  + q2.z*mk0[10] + q2.w*mk0[11];
            mB0 += q3.x*mk0[12] + q3.y*mk0[13] + q3.z*mk0[14] + q3.w*mk0[15];
            mB1  = q0.x*mk1[0]  + q0.y*mk1[1]  + q0.z*mk1[2]  + q0.w*mk1[3];
            mB1 += q1.x*mk1[4]  + q1.y*mk1[5]  + q1.z*mk1[6]  + q1.w*mk1[7];
            mB1 += q2.x*mk1[8]  + q2.y*mk1[9]  + q2.z*mk1[10] + q2.w*mk1[11];
            mB1 += q3.x*mk1[12] + q3.y*mk1[13] + q3.z*mk1[14] + q3.w*mk1[15];
        }
        accA0 = fmaf(attA * cA0, mA0, accA0);
        accA1 = fmaf(attA * cA1, mA1, accA1);
        accB0 = fmaf(attB * cB0, mB0, accB0);
        accB1 = fmaf(attB * cB1, mB1, accB1);
        asumA += attA; asumB += attB;
    }

    {
        const float invA = 1.0f / asumA, invB = 1.0f / asumB;
        ushort_t* crA = comb + rA * CSTRIDE;
        ushort_t* crB = comb + rB * CSTRIDE;
        crA[lane + 128] = f2bf(accA0 * invA);
        crA[lane + 192] = f2bf(accA1 * invA);
        crB[lane + 128] = f2bf(accB0 * invB);
        crB[lane + 192] = f2bf(accB1 * invB);
    }

    // ---------------- phase B ----------------
    const int l16 = lane & 15, quad = lane >> 4;
    const int Ntiles = (E + 15) >> 4;

    // prefetch this wave's first W tile BEFORE the barrier (hides L2 latency)
    v8s bfr[8];
    {
        const int nt0 = (wave < Ntiles) ? wave : 0;
        const ushort_t* wrow = Wb + (size_t)(nt0 * 16 + l16) * 256 + quad * 8;
        #pragma unroll
        for (int kk = 0; kk < 8; kk++)
            bfr[kk] = *(const v8s*)(wrow + kk * 32);
    }

    __syncthreads();

    // A-fragments: A[m=l16][k = kk*32 + quad*8 + j]
    v8s afr[8];
    #pragma unroll
    for (int kk = 0; kk < 8; kk++)
        afr[kk] = *(const v8s*)(comb + l16 * CSTRIDE + kk * 32 + quad * 8);

    for (int nt = wave; nt < Ntiles; nt += 8) {
        if (nt != wave) {
            const ushort_t* wrow = Wb + (size_t)(nt * 16 + l16) * 256 + quad * 8;
            #pragma unroll
            for (int kk = 0; kk < 8; kk++)
                bfr[kk] = *(const v8s*)(wrow + kk * 32);
        }
        v4f acc = {0.f, 0.f, 0.f, 0.f};
        #pragma unroll
        for (int kk = 0; kk < 8; kk++)
            acc = __builtin_amdgcn_mfma_f32_16x16x32_bf16(afr[kk], bfr[kk], acc, 0, 0, 0);
        const int gcol = nt * 16 + l16;
        if (gcol < E) {
            #pragma unroll
            for (int rr = 0; rr < 4; rr++) {
                const int grow = b0 + quad * 4 + rr;
                if (grow < B)
                    out[(size_t)grow * E + gcol] = fmaxf(acc[rr], 0.f);
            }
        }
    }
}

extern "C" void kernel_launch(void* const* d_in, const int* in_sizes, int n_in,
                              void* d_out, int out_size, void* d_ws, size_t ws_size,
                              hipStream_t stream) {
    const int*   nodes        = (const int*)d_in[0];
    const int*   neigh_idx    = (const int*)d_in[1];
    const float* self_table   = (const float*)d_in[2];
    const float* neigh_table  = (const float*)d_in[3];
    const float* center       = (const float*)d_in[4];
    const float* cluster_mask = (const float*)d_in[5];
    const float* weight       = (const float*)d_in[6];
    const float* alpha        = (const float*)d_in[7];
    float* out = (float*)d_out;

    int B = in_sizes[0];
    int S = in_sizes[1] / B;
    int E = in_sizes[6] / (2 * FDIM);

    int Np = ((E + 15) / 16) * 16;
    ushort_t* Wb = (ushort_t*)d_ws;   // Np x 256 bf16

    long totalW = (long)Np * 256;
    long validW = (long)E * 256;
    int blksW = (int)((totalW + 1023) / 1024);
    pack_weight<<<blksW, 256, 0, stream>>>(weight, Wb, totalW, validW);

    int nblk = (B + 15) / 16;
    fused_agg<<<nblk, 512, 0, stream>>>(
        nodes, neigh_idx, self_table, neigh_table, center, cluster_mask, alpha,
        Wb, out, B, S, E);
}

// Round 2
// 267.030 us; speedup vs baseline: 1.1114x; 1.1114x over previous
//
#include <hip/hip_runtime.h>
#include <hip/hip_bf16.h>

typedef unsigned short ushort_t;
typedef __attribute__((ext_vector_type(4))) float v4f;
typedef __attribute__((ext_vector_type(8))) short v8s;

#define FDIM 128
#define KCLUST 16
#define CSTRIDE 264   // combined-row stride in bf16 elems (264*2B = 528B -> rows offset by 4 banks)

__device__ __forceinline__ ushort_t f2bf(float x) {
    unsigned int u = __float_as_uint(x);
    unsigned int r = (u + 0x7fffu + ((u >> 16) & 1u)) >> 16;
    return (ushort_t)r;
}

__device__ __forceinline__ float wave_reduce_sum(float v) {
    #pragma unroll
    for (int off = 32; off > 0; off >>= 1) v += __shfl_xor(v, off, 64);
    return v;
}

// ---------------------------------------------------------------------------
// Kernel 1: cast weight (E x 256 f32) -> bf16, padded to Np rows (zeros).
// ---------------------------------------------------------------------------
__global__ void pack_weight(const float* __restrict__ W, ushort_t* __restrict__ Wb,
                            long total, long valid) {
    long i = ((long)blockIdx.x * blockDim.x + threadIdx.x) * 4;
    if (i >= total) return;
    float4 v;
    if (i < valid) v = *(const float4*)(W + i);
    else           v = make_float4(0.f, 0.f, 0.f, 0.f);
    ushort_t* dst = Wb + i;
    dst[0] = f2bf(v.x); dst[1] = f2bf(v.y); dst[2] = f2bf(v.z); dst[3] = f2bf(v.w);
}

// ---------------------------------------------------------------------------
// Kernel 2 (fused), v3: identical structure to v2 (512 thr = 8 waves, 2
// interleaved rows per wave) but with __launch_bounds__(512, 2):
//   v2's (512,4) capped VGPRs at 64 -> the ~115-reg live set (cc[32]+mk[32]
//   constants + dual row chains) spilled to scratch (WRITE_SIZE 10->52MB).
//   (512,2) caps at 128: fits without spill, still guarantees 2 blocks/CU.
// ---------------------------------------------------------------------------
__global__ __launch_bounds__(512, 2) void fused_agg(
    const int* __restrict__ nodes, const int* __restrict__ neigh_idx,
    const float* __restrict__ self_table, const float* __restrict__ neigh_table,
    const float* __restrict__ center, const float* __restrict__ cluster_mask,
    const float* __restrict__ alpha, const ushort_t* __restrict__ Wb,
    float* __restrict__ out, int B, int S, int E) {

    __shared__ __align__(16) ushort_t comb[16 * CSTRIDE];
    __shared__ __align__(16) float nbuf[16 * 144];   // per-row swizzled neigh vec
    __shared__ __align__(16) float qbuf[16 * 16];    // per-row q[16]

    const int t = threadIdx.x;
    const int lane = t & 63, wave = t >> 6;   // 8 waves
    const int kcl = lane & 15, blk = lane >> 4;

    // per-lane constants (feature layout: this lane owns features lane, lane+64)
    const float as0 = alpha[lane],       as1 = alpha[lane + 64];
    const float an0 = alpha[128 + lane], an1 = alpha[192 + lane];

    // center in cluster layout: cc[j] = center[kcl][blk*32 + j]
    float cc[32];
    {
        const float* cb = center + kcl * FDIM + blk * 32;
        #pragma unroll
        for (int j = 0; j < 32; j += 4) {
            float4 v = *(const float4*)(cb + j);
            cc[j] = v.x; cc[j+1] = v.y; cc[j+2] = v.z; cc[j+3] = v.w;
        }
    }
    // mask in feature layout: mk0[k] = mask[k][lane], mk1[k] = mask[k][lane+64]
    float mk0[KCLUST], mk1[KCLUST];
    #pragma unroll
    for (int kk = 0; kk < KCLUST; kk++) {
        mk0[kk] = cluster_mask[kk * FDIM + lane];
        mk1[kk] = cluster_mask[kk * FDIM + 64 + lane];
    }

    const int b0 = blockIdx.x * 16;
    const int rA = wave * 2, rB = rA + 1;
    int bA = b0 + rA, bB = b0 + rB;
    if (bA >= B) bA = B - 1;   // clamp loads; stores are guarded
    if (bB >= B) bB = B - 1;

    float* const nbA = nbuf + rA * 144;
    float* const nbB = nbuf + rB * 144;
    float* const qbA = qbuf + rA * 16;
    float* const qbB = qbuf + rB * 16;

    // ---------------- phase A ----------------
    float lsA, lsB;
    {
        size_t ndA = (size_t)nodes[bA], ndB = (size_t)nodes[bB];
        float sA0 = self_table[ndA * FDIM + lane];
        float sA1 = self_table[ndA * FDIM + 64 + lane];
        float sB0 = self_table[ndB * FDIM + lane];
        float sB1 = self_table[ndB * FDIM + 64 + lane];
        lsA = wave_reduce_sum(sA0 * as0 + sA1 * as1);
        lsB = wave_reduce_sum(sB0 * as0 + sB1 * as1);
        ushort_t* crA = comb + rA * CSTRIDE;
        ushort_t* crB = comb + rB * CSTRIDE;
        crA[lane] = f2bf(sA0); crA[lane + 64] = f2bf(sA1);
        crB[lane] = f2bf(sB0); crB[lane + 64] = f2bf(sB1);
    }

    // preload neighbor indices into lanes (S <= 64; S=10 here)
    int gIA = 0, gIB = 0;
    if (lane < S) {
        gIA = neigh_idx[(size_t)bA * S + lane];
        gIB = neigh_idx[(size_t)bB * S + lane];
    }

    float accA0 = 0.f, accA1 = 0.f, asumA = 0.f;
    float accB0 = 0.f, accB1 = 0.f, asumB = 0.f;

    // software pipeline: preload s=0 for both rows
    int iA = __shfl(gIA, 0, 64);
    int iB = __shfl(gIB, 0, 64);
    float nA0 = neigh_table[(size_t)iA * FDIM + lane];
    float nA1 = neigh_table[(size_t)iA * FDIM + 64 + lane];
    float nB0 = neigh_table[(size_t)iB * FDIM + lane];
    float nB1 = neigh_table[(size_t)iB * FDIM + 64 + lane];

    for (int s = 0; s < S; s++) {
        const float cA0 = nA0, cA1 = nA1, cB0 = nB0, cB1 = nB1;
        if (s + 1 < S) {
            iA = __shfl(gIA, s + 1, 64);
            iB = __shfl(gIB, s + 1, 64);
            nA0 = neigh_table[(size_t)iA * FDIM + lane];
            nA1 = neigh_table[(size_t)iA * FDIM + 64 + lane];
            nB0 = neigh_table[(size_t)iB * FDIM + lane];
            nB1 = neigh_table[(size_t)iB * FDIM + 64 + lane];
        }
        // stage neigh vecs (swizzled: float f at idx f + (f>>5)*4)
        {
            const int f1 = lane + (lane >> 5) * 4;
            const int f2 = (lane + 64) + ((lane + 64) >> 5) * 4;
            nbA[f1] = cA0; nbA[f2] = cA1;
            nbB[f1] = cB0; nbB[f2] = cB1;
        }
        // attention logits, both rows (interleaved butterflies)
        float lnA = cA0 * an0 + cA1 * an1;
        float lnB = cB0 * an0 + cB1 * an1;
        #pragma unroll
        for (int off = 32; off > 0; off >>= 1) {
            lnA += __shfl_xor(lnA, off, 64);
            lnB += __shfl_xor(lnB, off, 64);
        }
        const float attA = __expf(fmaxf(lsA + lnA, 0.f));
        const float attB = __expf(fmaxf(lsB + lnB, 0.f));

        // cluster layout: d_k = sum_j (n_j - c_kj)^2 over this blk's 32 feats
        float dA = 0.f, dB = 0.f;
        {
            const float* na = nbA + blk * 36;
            const float* nb2 = nbB + blk * 36;
            #pragma unroll
            for (int i = 0; i < 8; i++) {
                float4 a4 = *(const float4*)(na + i * 4);
                float4 b4 = *(const float4*)(nb2 + i * 4);
                float u;
                u = a4.x - cc[i*4+0]; dA = fmaf(u, u, dA);
                u = a4.y - cc[i*4+1]; dA = fmaf(u, u, dA);
                u = a4.z - cc[i*4+2]; dA = fmaf(u, u, dA);
                u = a4.w - cc[i*4+3]; dA = fmaf(u, u, dA);
                u = b4.x - cc[i*4+0]; dB = fmaf(u, u, dB);
                u = b4.y - cc[i*4+1]; dB = fmaf(u, u, dB);
                u = b4.z - cc[i*4+2]; dB = fmaf(u, u, dB);
                u = b4.w - cc[i*4+3]; dB = fmaf(u, u, dB);
            }
        }
        dA += __shfl_xor(dA, 16, 64); dA += __shfl_xor(dA, 32, 64);
        dB += __shfl_xor(dB, 16, 64); dB += __shfl_xor(dB, 32, 64);
        const float qA = 1.0f / (dA + 1.0f);
        const float qB = 1.0f / (dB + 1.0f);
        if (lane < 16) { qbA[lane] = qA; qbB[lane] = qB; }

        // feature layout: m_f = sum_k q_k * mask[k][f]  (A then B to limit regs)
        float mA0, mA1;
        {
            float4 q0 = *(const float4*)(qbA + 0);
            float4 q1 = *(const float4*)(qbA + 4);
            float4 q2 = *(const float4*)(qbA + 8);
            float4 q3 = *(const float4*)(qbA + 12);
            mA0  = q0.x*mk0[0]  + q0.y*mk0[1]  + q0.z*mk0[2]  + q0.w*mk0[3];
            mA0 += q1.x*mk0[4]  + q1.y*mk0[5]  + q1.z*mk0[6]  + q1.w*mk0[7];
            mA0 += q2.x*mk0[8]  + q2.y*mk0[9]  + q2.z*mk0[10] + q2.w*mk0[11];
            mA0 += q3.x*mk0[12] + q3.y*mk0[13] + q3.z*mk0[14] + q3.w*mk0[15];
            mA1  = q0.x*mk1[0]  + q0.y*mk1[1]  + q0.z*mk1[2]  + q0.w*mk1[3];
            mA1 += q1.x*mk1[4]  + q1.y*mk1[5]  + q1.z*mk1[6]  + q1.w*mk1[7];
            mA1 += q2.x*mk1[8]  + q2.y*mk1[9]  + q2.z*mk1[10] + q2.w*mk1[11];
            mA1 += q3.x*mk1[12] + q3.y*mk1[13] + q3.z*mk1[14] + q3.w*mk1[15];
        }
        float mB0, mB1;
        {
            float4 q0 = *(const float4*)(qbB + 0);
            float4 q1 = *(const float4*)(qbB + 4);
            float4 q2 = *(const float4*)(qbB + 8);
            float4 q3 = *(const float4*)(qbB + 12);
            mB0  = q0.x*mk0[0]  + q0.y*mk0[1]  + q0.z*mk0[2]  + q0.w*mk0[3];
            mB0 += q1.x*mk0[4]  + q1.y*mk0[5]  + q1.z*mk0[6]  + q1.w*mk0[7];
            mB0 += q2.x*mk0[8]  + q2.y*mk0[9]  + q2.z*mk0[10] + q2.w*mk0[11];
            mB0 += q3.x*mk0[12] + q3.y*mk0[13] + q3.z*mk0[14] + q3.w*mk0[15];
            mB1  = q0.x*mk1[0]  + q0.y*mk1[1]  + q0.z*mk1[2]  + q0.w*mk1[3];
            mB1 += q1.x*mk1[4]  + q1.y*mk1[5]  + q1.z*mk1[6]  + q1.w*mk1[7];
            mB1 += q2.x*mk1[8]  + q2.y*mk1[9]  + q2.z*mk1[10] + q2.w*mk1[11];
            mB1 += q3.x*mk1[12] + q3.y*mk1[13] + q3.z*mk1[14] + q3.w*mk1[15];
        }
        accA0 = fmaf(attA * cA0, mA0, accA0);
        accA1 = fmaf(attA * cA1, mA1, accA1);
        accB0 = fmaf(attB * cB0, mB0, accB0);
        accB1 = fmaf(attB * cB1, mB1, accB1);
        asumA += attA; asumB += attB;
    }

    {
        const float invA = 1.0f / asumA, invB = 1.0f / asumB;
        ushort_t* crA = comb + rA * CSTRIDE;
        ushort_t* crB = comb + rB * CSTRIDE;
        crA[lane + 128] = f2bf(accA0 * invA);
        crA[lane + 192] = f2bf(accA1 * invA);
        crB[lane + 128] = f2bf(accB0 * invB);
        crB[lane + 192] = f2bf(accB1 * invB);
    }

    // ---------------- phase B ----------------
    const int l16 = lane & 15, quad = lane >> 4;
    const int Ntiles = (E + 15) >> 4;

    // prefetch this wave's first W tile BEFORE the barrier (hides L2 latency)
    v8s bfr[8];
    {
        const int nt0 = (wave < Ntiles) ? wave : 0;
        const ushort_t* wrow = Wb + (size_t)(nt0 * 16 + l16) * 256 + quad * 8;
        #pragma unroll
        for (int kk = 0; kk < 8; kk++)
            bfr[kk] = *(const v8s*)(wrow + kk * 32);
    }

    __syncthreads();

    // A-fragments: A[m=l16][k = kk*32 + quad*8 + j]
    v8s afr[8];
    #pragma unroll
    for (int kk = 0; kk < 8; kk++)
        afr[kk] = *(const v8s*)(comb + l16 * CSTRIDE + kk * 32 + quad * 8);

    for (int nt = wave; nt < Ntiles; nt += 8) {
        if (nt != wave) {
            const ushort_t* wrow = Wb + (size_t)(nt * 16 + l16) * 256 + quad * 8;
            #pragma unroll
            for (int kk = 0; kk < 8; kk++)
                bfr[kk] = *(const v8s*)(wrow + kk * 32);
        }
        v4f acc = {0.f, 0.f, 0.f, 0.f};
        #pragma unroll
        for (int kk = 0; kk < 8; kk++)
            acc = __builtin_amdgcn_mfma_f32_16x16x32_bf16(afr[kk], bfr[kk], acc, 0, 0, 0);
        const int gcol = nt * 16 + l16;
        if (gcol < E) {
            #pragma unroll
            for (int rr = 0; rr < 4; rr++) {
                const int grow = b0 + quad * 4 + rr;
                if (grow < B)
                    out[(size_t)grow * E + gcol] = fmaxf(acc[rr], 0.f);
            }
        }
    }
}

extern "C" void kernel_launch(void* const* d_in, const int* in_sizes, int n_in,
                              void* d_out, int out_size, void* d_ws, size_t ws_size,
                              hipStream_t stream) {
    const int*   nodes        = (const int*)d_in[0];
    const int*   neigh_idx    = (const int*)d_in[1];
    const float* self_table   = (const float*)d_in[2];
    const float* neigh_table  = (const float*)d_in[3];
    const float* center       = (const float*)d_in[4];
    const float* cluster_mask = (const float*)d_in[5];
    const float* weight       = (const float*)d_in[6];
    const float* alpha        = (const float*)d_in[7];
    float* out = (float*)d_out;

    int B = in_sizes[0];
    int S = in_sizes[1] / B;
    int E = in_sizes[6] / (2 * FDIM);

    int Np = ((E + 15) / 16) * 16;
    ushort_t* Wb = (ushort_t*)d_ws;   // Np x 256 bf16

    long totalW = (long)Np * 256;
    long validW = (long)E * 256;
    int blksW = (int)((totalW + 1023) / 1024);
    pack_weight<<<blksW, 256, 0, stream>>>(weight, Wb, totalW, validW);

    int nblk = (B + 15) / 16;
    fused_agg<<<nblk, 512, 0, stream>>>(
        nodes, neigh_idx, self_table, neigh_table, center, cluster_mask, alpha,
        Wb, out, B, S, E);
}

// Round 3
// 233.411 us; speedup vs baseline: 1.2715x; 1.1440x over previous
//
#include <hip/hip_runtime.h>
#include <hip/hip_bf16.h>

typedef unsigned short ushort_t;
typedef __attribute__((ext_vector_type(4))) float v4f;
typedef __attribute__((ext_vector_type(8))) short v8s;

#define FDIM 128
#define KCLUST 16
#define CSTRIDE 264   // combined-row stride in bf16 elems (264*2B = 528B)

__device__ __forceinline__ ushort_t f2bf(float x) {
    unsigned int u = __float_as_uint(x);
    unsigned int r = (u + 0x7fffu + ((u >> 16) & 1u)) >> 16;
    return (ushort_t)r;
}
__device__ __forceinline__ float bf2f(ushort_t h) {
    return __uint_as_float((unsigned int)h << 16);
}

union V8U { v8s v; ushort_t u[8]; };

// ---------------------------------------------------------------------------
// Kernel 1: cast weight (E x 256 f32) -> bf16, padded to Np rows (zeros).
// ---------------------------------------------------------------------------
__global__ void pack_weight(const float* __restrict__ W, ushort_t* __restrict__ Wb,
                            long total, long valid) {
    long i = ((long)blockIdx.x * blockDim.x + threadIdx.x) * 4;
    if (i >= total) return;
    float4 v;
    if (i < valid) v = *(const float4*)(W + i);
    else           v = make_float4(0.f, 0.f, 0.f, 0.f);
    ushort_t* dst = Wb + i;
    dst[0] = f2bf(v.x); dst[1] = f2bf(v.y); dst[2] = f2bf(v.z); dst[3] = f2bf(v.w);
}

// ---------------------------------------------------------------------------
// Kernel 2 (fused), v4: MFMA-ized cluster math.
//   Block = 16 rows, 512 threads (8 waves). Thread owns (row = t>>5, 4 feats).
//   Per s: all threads gather/stage N (bf16 XOR-swizzled + f32) and butterfly
//   logit/n2 -> barrier -> wave0 computes cross[16,16] via 4 MFMA and writes
//   q as split-bf16 (hi+lo) -> barrier -> each wave computes its 16-feature
//   m-tile via 3 MFMA (q_hi*mask_hi + q_lo*mask_hi + q_hi*mask_lo) and
//   accumulates att*n*m in f32 registers (D-layout). 2 barriers/s.
//   This removes the 16x LDS read amplification of the per-row d-loop and
//   the 64 FMA/row/s of d+m math (moved to the ~0.5%-utilized MFMA pipe).
// ---------------------------------------------------------------------------
__global__ __launch_bounds__(512, 2) void fused_agg(
    const int* __restrict__ nodes, const int* __restrict__ neigh_idx,
    const float* __restrict__ self_table, const float* __restrict__ neigh_table,
    const float* __restrict__ center, const float* __restrict__ cluster_mask,
    const float* __restrict__ alpha, const ushort_t* __restrict__ Wb,
    float* __restrict__ out, int B, int S, int E) {

    __shared__ __align__(16) ushort_t comb[16 * CSTRIDE];     // 16896 B
    __shared__ __align__(16) ushort_t nbf[2][16 * 128];       // 8192 B (swizzled bf16 N)
    __shared__ __align__(16) float    nf32[2][16 * 132];      // 16896 B (f32 N, pad 132)
    __shared__ __align__(16) float    attL[2][16];
    __shared__ __align__(16) float    n2L[2][16];
    __shared__ __align__(16) ushort_t qhi[16 * 16];           // 512 B
    __shared__ __align__(16) ushort_t qlo[16 * 16];           // 512 B
    __shared__ __align__(16) float    zslot[4];               // 16 B of zeros
    __shared__ __align__(16) float    invL[16];

    const int t    = threadIdx.x;
    const int lane = t & 63, wave = t >> 6;   // 8 waves
    const int row  = t >> 5;                  // 0..15 (2 rows per wave)
    const int fq   = t & 31;                  // feat-quad within row
    const int f0   = fq << 2;                 // first of this thread's 4 feats
    const int l16  = lane & 15, quad = lane >> 4;

    if (t < 4) zslot[t] = 0.f;

    const int b0 = blockIdx.x * 16;
    int b = b0 + row; if (b >= B) b = B - 1;  // clamp loads; stores guarded

    const float4 aS = *(const float4*)(alpha + f0);
    const float4 aN = *(const float4*)(alpha + FDIM + f0);

    // ---- self features: stage to comb (bf16) + logit_self butterfly ----
    float ls;
    {
        size_t node = (size_t)nodes[b];
        float4 sf = *(const float4*)(self_table + node * FDIM + f0);
        ushort_t h0 = f2bf(sf.x), h1 = f2bf(sf.y), h2 = f2bf(sf.z), h3 = f2bf(sf.w);
        uint2 pk;
        pk.x = (unsigned)h0 | ((unsigned)h1 << 16);
        pk.y = (unsigned)h2 | ((unsigned)h3 << 16);
        *(uint2*)(comb + row * CSTRIDE + f0) = pk;
        ls = sf.x * aS.x + sf.y * aS.y + sf.z * aS.z + sf.w * aS.w;
        #pragma unroll
        for (int off = 1; off <= 16; off <<= 1) ls += __shfl_xor(ls, off, 64);
    }

    // ---- wave 0: center B-fragments (bf16) + c2 (exact f32) ----
    v8s cbf[4]; float c2v = 0.f;
    if (wave == 0) {
        const float* crow = center + l16 * FDIM;
        #pragma unroll
        for (int kk = 0; kk < 4; kk++) {
            const float* p = crow + kk * 32 + quad * 8;
            float4 x = *(const float4*)p;
            float4 y = *(const float4*)(p + 4);
            V8U pk;
            pk.u[0] = f2bf(x.x); pk.u[1] = f2bf(x.y); pk.u[2] = f2bf(x.z); pk.u[3] = f2bf(x.w);
            pk.u[4] = f2bf(y.x); pk.u[5] = f2bf(y.y); pk.u[6] = f2bf(y.z); pk.u[7] = f2bf(y.w);
            cbf[kk] = pk.v;
            c2v += x.x*x.x + x.y*x.y + x.z*x.z + x.w*x.w
                 + y.x*y.x + y.y*y.y + y.z*y.z + y.w*y.w;
        }
        c2v += __shfl_xor(c2v, 16, 64);   // reduce across quads
        c2v += __shfl_xor(c2v, 32, 64);
    }

    // ---- all waves: mask B-fragments for this wave's 16-feature tile ----
    // split bf16: mask = mhi + mlo (error ~2^-17)
    v8s mhi, mlo;
    {
        V8U ph, pl;
        const int fcol = wave * 16 + l16;   // 8 waves * 16 = 128 = FDIM
        #pragma unroll
        for (int j = 0; j < 8; j++) {
            float mv = (quad < 2) ? cluster_mask[(quad * 8 + j) * FDIM + fcol] : 0.f;
            ushort_t h = f2bf(mv);
            ph.u[j] = h;
            pl.u[j] = f2bf(mv - bf2f(h));
        }
        mhi = ph.v; mlo = pl.v;
    }

    // ---- neighbor gather pipeline ----
    int idx0 = neigh_idx[(size_t)b * S];
    float4 n4 = *(const float4*)(neigh_table + (size_t)idx0 * FDIM + f0);
    int idx_next = (S > 1) ? neigh_idx[(size_t)b * S + 1] : 0;

    float attsum = 0.f;
    float acc0 = 0.f, acc1 = 0.f, acc2 = 0.f, acc3 = 0.f;  // rows quad*4+r, col wave*16+l16

    for (int s = 0; s < S; s++) {
        const int buf = s & 1;
        const float4 cur = n4;
        if (s + 1 < S) {
            n4 = *(const float4*)(neigh_table + (size_t)idx_next * FDIM + f0);
            if (s + 2 < S) idx_next = neigh_idx[(size_t)b * S + s + 2];
        }

        // stage f32 N
        *(float4*)(nf32[buf] + row * 132 + f0) = cur;
        // stage bf16 N, XOR-swizzled 16B slots (conflict-free A-frag reads)
        {
            ushort_t h0 = f2bf(cur.x), h1 = f2bf(cur.y), h2 = f2bf(cur.z), h3 = f2bf(cur.w);
            uint2 pk;
            pk.x = (unsigned)h0 | ((unsigned)h1 << 16);
            pk.y = (unsigned)h2 | ((unsigned)h3 << 16);
            const int slot = (fq >> 1) ^ (row & 15);
            *(uint2*)((char*)(nbf[buf]) + row * 256 + slot * 16 + (fq & 1) * 8) = pk;
        }
        // logit + n2 butterflies (within each row's 32 lanes)
        float pn = cur.x * aN.x + cur.y * aN.y + cur.z * aN.z + cur.w * aN.w;
        float p2 = cur.x * cur.x + cur.y * cur.y + cur.z * cur.z + cur.w * cur.w;
        #pragma unroll
        for (int off = 1; off <= 16; off <<= 1) {
            pn += __shfl_xor(pn, off, 64);
            p2 += __shfl_xor(p2, off, 64);
        }
        const float att = __expf(fmaxf(ls + pn, 0.f));
        attsum += att;
        if (fq == 0) { attL[buf][row] = att; n2L[buf][row] = p2; }
        __syncthreads();   // barrier 1: N, att, n2 ready

        if (wave == 0) {
            // cross[row][k] = sum_f N[row][f] * center[k][f], 4 MFMA over K=128
            v4f xacc = {0.f, 0.f, 0.f, 0.f};
            #pragma unroll
            for (int kk = 0; kk < 4; kk++) {
                const int sl = (kk * 4 + quad) ^ l16;
                v8s af = *(const v8s*)((char*)(nbf[buf]) + l16 * 256 + sl * 16);
                xacc = __builtin_amdgcn_mfma_f32_16x16x32_bf16(af, cbf[kk], xacc, 0, 0, 0);
            }
            const float4 n2r = *(const float4*)(&n2L[buf][quad * 4]);
            #pragma unroll
            for (int r = 0; r < 4; r++) {
                const float n2v = (r == 0) ? n2r.x : (r == 1) ? n2r.y : (r == 2) ? n2r.z : n2r.w;
                const float d  = n2v - 2.f * xacc[r] + c2v;
                const float qv = 1.f / (d + 1.f);
                const ushort_t h = f2bf(qv);
                qhi[(quad * 4 + r) * 16 + l16] = h;
                qlo[(quad * 4 + r) * 16 + l16] = f2bf(qv - bf2f(h));
            }
        }
        __syncthreads();   // barrier 2: q ready

        // m-tile: m[row][wave*16+l16] = sum_k q[row][k]*mask[k][f]
        // A-frag: lane l16 = row, quads 0,1 hold k=0..15, quads 2,3 read zeros
        v8s aqh = (quad < 2) ? *(const v8s*)((char*)qhi + l16 * 32 + quad * 16)
                             : *(const v8s*)zslot;
        v8s aql = (quad < 2) ? *(const v8s*)((char*)qlo + l16 * 32 + quad * 16)
                             : *(const v8s*)zslot;
        v4f mac = {0.f, 0.f, 0.f, 0.f};
        mac = __builtin_amdgcn_mfma_f32_16x16x32_bf16(aqh, mhi, mac, 0, 0, 0);
        mac = __builtin_amdgcn_mfma_f32_16x16x32_bf16(aql, mhi, mac, 0, 0, 0);
        mac = __builtin_amdgcn_mfma_f32_16x16x32_bf16(aqh, mlo, mac, 0, 0, 0);

        // accumulate att * n * m in f32 (D-layout: rows quad*4+r, col wave*16+l16)
        const float4 attr = *(const float4*)(&attL[buf][quad * 4]);
        const float* nfp = nf32[buf] + wave * 16 + l16;
        acc0 = fmaf(attr.x * mac[0], nfp[(quad * 4 + 0) * 132], acc0);
        acc1 = fmaf(attr.y * mac[1], nfp[(quad * 4 + 1) * 132], acc1);
        acc2 = fmaf(attr.z * mac[2], nfp[(quad * 4 + 2) * 132], acc2);
        acc3 = fmaf(attr.w * mac[3], nfp[(quad * 4 + 3) * 132], acc3);
    }

    // ---- normalize + write neigh-agg half of comb ----
    if (fq == 0) invL[row] = 1.f / attsum;
    __syncthreads();
    {
        const float4 invr = *(const float4*)(&invL[quad * 4]);
        ushort_t* cp = comb + 128 + wave * 16 + l16;
        cp[(quad * 4 + 0) * CSTRIDE] = f2bf(acc0 * invr.x);
        cp[(quad * 4 + 1) * CSTRIDE] = f2bf(acc1 * invr.y);
        cp[(quad * 4 + 2) * CSTRIDE] = f2bf(acc2 * invr.z);
        cp[(quad * 4 + 3) * CSTRIDE] = f2bf(acc3 * invr.w);
    }
    __syncthreads();

    // ---------------- phase B: out[16][E] = relu(comb @ Wb^T) ----------------
    const int Ntiles = (E + 15) >> 4;

    // prefetch this wave's first W tile before reading comb fragments
    v8s bfr[8];
    {
        const int nt0 = (wave < Ntiles) ? wave : 0;
        const ushort_t* wrow = Wb + (size_t)(nt0 * 16 + l16) * 256 + quad * 8;
        #pragma unroll
        for (int kk = 0; kk < 8; kk++)
            bfr[kk] = *(const v8s*)(wrow + kk * 32);
    }

    v8s afr[8];
    #pragma unroll
    for (int kk = 0; kk < 8; kk++)
        afr[kk] = *(const v8s*)(comb + l16 * CSTRIDE + kk * 32 + quad * 8);

    for (int nt = wave; nt < Ntiles; nt += 8) {
        if (nt != wave) {
            const ushort_t* wrow = Wb + (size_t)(nt * 16 + l16) * 256 + quad * 8;
            #pragma unroll
            for (int kk = 0; kk < 8; kk++)
                bfr[kk] = *(const v8s*)(wrow + kk * 32);
        }
        v4f acc = {0.f, 0.f, 0.f, 0.f};
        #pragma unroll
        for (int kk = 0; kk < 8; kk++)
            acc = __builtin_amdgcn_mfma_f32_16x16x32_bf16(afr[kk], bfr[kk], acc, 0, 0, 0);
        const int gcol = nt * 16 + l16;
        if (gcol < E) {
            #pragma unroll
            for (int rr = 0; rr < 4; rr++) {
                const int grow = b0 + quad * 4 + rr;
                if (grow < B)
                    out[(size_t)grow * E + gcol] = fmaxf(acc[rr], 0.f);
            }
        }
    }
}

extern "C" void kernel_launch(void* const* d_in, const int* in_sizes, int n_in,
                              void* d_out, int out_size, void* d_ws, size_t ws_size,
                              hipStream_t stream) {
    const int*   nodes        = (const int*)d_in[0];
    const int*   neigh_idx    = (const int*)d_in[1];
    const float* self_table   = (const float*)d_in[2];
    const float* neigh_table  = (const float*)d_in[3];
    const float* center       = (const float*)d_in[4];
    const float* cluster_mask = (const float*)d_in[5];
    const float* weight       = (const float*)d_in[6];
    const float* alpha        = (const float*)d_in[7];
    float* out = (float*)d_out;

    int B = in_sizes[0];
    int S = in_sizes[1] / B;
    int E = in_sizes[6] / (2 * FDIM);

    int Np = ((E + 15) / 16) * 16;
    ushort_t* Wb = (ushort_t*)d_ws;   // Np x 256 bf16

    long totalW = (long)Np * 256;
    long validW = (long)E * 256;
    int blksW = (int)((totalW + 1023) / 1024);
    pack_weight<<<blksW, 256, 0, stream>>>(weight, Wb, totalW, validW);

    int nblk = (B + 15) / 16;
    fused_agg<<<nblk, 512, 0, stream>>>(
        nodes, neigh_idx, self_table, neigh_table, center, cluster_mask, alpha,
        Wb, out, B, S, E);
}